// Round 4
// baseline (243.813 us; speedup 1.0000x reference)
//
#include <hip/hip_runtime.h>

#define BS 32
#define NA 8400
#define NMAX 100
#define NC 80
#define TOPK 13
#define EPSF 1e-9f
#define CAP 1024     // max in-gt anchors per row; true max ~420 (mean 336, sigma 18)
#define NSTRIP 64
#define STRIP_INV 0.1f   // 10px y-strips over [0,640)

// out layout (float32, concatenated in reference return order)
#define OFF_LBL  0
#define OFF_BOX  (BS*NA)                       // 268800
#define OFF_SCR  (BS*NA + BS*NA*4)             // 1344000
#define OFF_POS  (BS*NA + BS*NA*4 + BS*NA*NC)  // 22848000

__device__ __forceinline__ float iou_fn(float gx1, float gy1, float gx2, float gy2,
                                        float px1, float py1, float px2, float py2) {
    float lx = fmaxf(gx1, px1), ly = fmaxf(gy1, py1);
    float rx = fminf(gx2, px2), ry = fminf(gy2, py2);
    float w = fmaxf(rx - lx, 0.f), h = fmaxf(ry - ly, 0.f);
    float inter = w * h;
    float aa = (gx2 - gx1) * (gy2 - gy1);
    float ab = (px2 - px1) * (py2 - py1);
    return inter / (aa + ab - inter + EPSF);
}

// Single block: bin anchors into 64 y-strips, emit strip-sorted (x,y) + index
// arrays so topk blocks only scan strips overlapping their gt's y-range.
// Order within a strip is nondeterministic — harmless, selection uses u64 keys.
__global__ __launch_bounds__(256) void bin_kernel(
    const float* __restrict__ anchor_points,
    int* __restrict__ strip_off, float2* __restrict__ sAP, int* __restrict__ sIdx)
{
    __shared__ int cnt[NSTRIP];
    __shared__ int cur[NSTRIP];
    int t = threadIdx.x;
    if (t < NSTRIP) cnt[t] = 0;
    __syncthreads();
    const float2* ap2 = (const float2*)anchor_points;
    for (int a = t; a < NA; a += 256) {
        int s = (int)(ap2[a].y * STRIP_INV);
        s = s < 0 ? 0 : (s > NSTRIP - 1 ? NSTRIP - 1 : s);
        atomicAdd(&cnt[s], 1);
    }
    __syncthreads();
    if (t == 0) {
        int acc = 0;
        for (int s = 0; s < NSTRIP; s++) {
            cur[s] = acc; strip_off[s] = acc; acc += cnt[s];
        }
        strip_off[NSTRIP] = acc;   // == NA
    }
    __syncthreads();
    for (int a = t; a < NA; a += 256) {
        float2 p = ap2[a];
        int s = (int)(p.y * STRIP_INV);
        s = s < 0 ? 0 : (s > NSTRIP - 1 ? NSTRIP - 1 : s);
        int pos = atomicAdd(&cur[s], 1);
        sAP[pos] = p;
        sIdx[pos] = a;
    }
}

// One block per (b, j) gt row.
// Phase 1a: scan ONLY the y-strips overlapping (gy1,gy2); exact in-gt test;
//           ballot-aggregated append (one LDS atomic per wave-iteration).
// Phase 1b: ~340 candidates -> 2 strided iterations; scattered pred loads
//           issued concurrently (full MLP).
// Phase 2:  wave 0 only — per-lane sorted top-13 in registers, 13 rounds of
//           shfl_xor max-merge. One packed atomic per pick.
// Key packing: (metric_bits<<32) | (NA-idx) -> u64 order == value desc, index
// asc (exact jax top_k tie-break).
__global__ __launch_bounds__(256) void topk_kernel(
    const float* __restrict__ pred_scores,   // BS,NA,NC
    const float* __restrict__ pred_bboxes,   // BS,NA,4
    const int*   __restrict__ gt_labels,     // BS,NMAX,1
    const float* __restrict__ gt_bboxes,     // BS,NMAX,4
    const float* __restrict__ mask_gt,       // BS,NMAX,1
    const int*   __restrict__ strip_off,
    const float2* __restrict__ sAP,
    const int*   __restrict__ sIdx,
    unsigned int* __restrict__ claims)       // BS,NA packed: (count<<16)|jsum
{
    int row = blockIdx.x;
    int b = row / NMAX, j = row % NMAX;
    if (mask_gt[row] <= 0.f) return;  // masked gt contributes no claims

    __shared__ unsigned long long cand[CAP];
    __shared__ unsigned short aidx[CAP];
    __shared__ int ncand;

    int t = threadIdx.x;
    if (t == 0) ncand = 0;
    __syncthreads();

    const float* gb = gt_bboxes + (size_t)row * 4;
    float gx1 = gb[0], gy1 = gb[1], gx2 = gb[2], gy2 = gb[3];
    int lab = gt_labels[row];

    // strip range covering (gy1, gy2): float mul + floor are monotone, so any
    // anchor passing the exact test lies within [s_lo, s_hi].
    int s_lo = (int)(gy1 * STRIP_INV); s_lo = s_lo < 0 ? 0 : (s_lo > NSTRIP-1 ? NSTRIP-1 : s_lo);
    int s_hi = (int)(gy2 * STRIP_INV); s_hi = s_hi < 0 ? 0 : (s_hi > NSTRIP-1 ? NSTRIP-1 : s_hi);
    int lo = strip_off[s_lo], hi = strip_off[s_hi + 1];

    int lane = t & 63;
    for (int base = lo; base < hi; base += 256) {
        int p = base + t;
        bool hit = false;
        int a = 0;
        if (p < hi) {
            float2 ap = sAP[p];
            a = sIdx[p];
            hit = (ap.x - gx1 > EPSF) && (ap.y - gy1 > EPSF) &&
                  (gx2 - ap.x > EPSF) && (gy2 - ap.y > EPSF);
        }
        unsigned long long m = __ballot(hit);
        if (m != 0ULL) {               // wave-uniform branch
            int basepos = 0;
            if (lane == 0) basepos = atomicAdd(&ncand, __popcll(m));
            basepos = __shfl(basepos, 0, 64);
            if (hit) {
                int my = basepos + __popcll(m & ((1ULL << lane) - 1ULL));
                if (my < CAP) aidx[my] = (unsigned short)a;
            }
        }
    }
    __syncthreads();
    int n = ncand < CAP ? ncand : CAP;

    // Phase 1b: scattered loads for all candidates issued concurrently
    const float4* pb4 = (const float4*)pred_bboxes;
    for (int p = t; p < n; p += 256) {
        int a = aidx[p];
        float4 pb = pb4[b * NA + a];
        float iou = iou_fn(gx1, gy1, gx2, gy2, pb.x, pb.y, pb.z, pb.w);
        float s = pred_scores[((size_t)b * NA + a) * NC + lab];
        float i2 = iou * iou;
        float m = s * (i2 * i2 * i2);
        cand[p] = (m > 0.f)
                    ? (((unsigned long long)__float_as_uint(m) << 32) |
                       (unsigned int)(NA - a))
                    : 0ULL;
    }
    __syncthreads();

    if (t >= 64) return;  // phase 2 is wave 0 only

    unsigned long long loc[TOPK];
    #pragma unroll
    for (int i = 0; i < TOPK; i++) loc[i] = 0ULL;
    for (int p = t; p < n; p += 64) {
        unsigned long long k = cand[p];
        #pragma unroll
        for (int i = 0; i < TOPK; i++) {
            if (k > loc[i]) { unsigned long long tmp = loc[i]; loc[i] = k; k = tmp; }
        }
    }

    int head = 0;
    for (int r = 0; r < TOPK; r++) {
        unsigned long long h = (head < TOPK) ? loc[head] : 0ULL;
        unsigned long long m = h;
        #pragma unroll
        for (int s = 32; s > 0; s >>= 1) {
            unsigned long long o = __shfl_xor(m, s, 64);
            m = o > m ? o : m;
        }
        if (m == 0ULL) break;  // fewer than 13 positive candidates
        unsigned long long ball = __ballot(h == m);  // keys distinct -> one lane
        int winner = (int)__builtin_ctzll(ball);
        if (t == winner) {
            head++;
            int a = NA - (int)(unsigned int)(m & 0xFFFFFFFFULL);
            atomicAdd(&claims[b * NA + a], (1u << 16) | (unsigned int)j);
        }
    }
}

// Grid (ceil(NA/256), BS). Stage this batch's gt boxes+labels in LDS so the
// multi-claim argmax loop (and final gt lookup) never touches global memory.
__global__ __launch_bounds__(256) void resolve_kernel(
    const float* __restrict__ pred_scores,
    const float* __restrict__ pred_bboxes,
    const int*   __restrict__ gt_labels,
    const float* __restrict__ gt_bboxes,
    const unsigned int* __restrict__ claims,
    int* __restrict__ assigned_j, float* __restrict__ a_align,
    unsigned int* __restrict__ pa_bits, unsigned int* __restrict__ po_bits)
{
    __shared__ float4 gtb[NMAX];
    __shared__ int    glab[NMAX];
    int b = blockIdx.y;
    int t = threadIdx.x;
    if (t < NMAX) {
        gtb[t]  = ((const float4*)gt_bboxes)[b * NMAX + t];
        glab[t] = gt_labels[b * NMAX + t];
    }
    __syncthreads();

    int ai = blockIdx.x * 256 + t;
    if (ai >= NA) return;
    int idx = b * NA + ai;
    unsigned int pk = claims[idx];
    if (pk == 0u) { assigned_j[idx] = -1; a_align[idx] = 0.f; return; }

    float4 pb = ((const float4*)pred_bboxes)[idx];

    int js;
    if ((pk >> 16) == 1u) {
        js = (int)(pk & 0xFFFFu);
    } else {
        // reference: overlaps.argmax(axis=1) over ALL gts, first-max wins
        float best = -1.f; js = 0;
        for (int j = 0; j < NMAX; j++) {
            float4 g = gtb[j];
            float v = iou_fn(g.x, g.y, g.z, g.w, pb.x, pb.y, pb.z, pb.w);
            if (v > best) { best = v; js = j; }
        }
    }
    float4 g = gtb[js];
    float iou = iou_fn(g.x, g.y, g.z, g.w, pb.x, pb.y, pb.z, pb.w);
    int lab = glab[js];
    float s = pred_scores[(size_t)idx * NC + lab];
    float i2 = iou * iou;
    float align = s * (i2 * i2 * i2);   // UNMASKED align metric (reference semantics)
    assigned_j[idx] = js; a_align[idx] = align;
    // non-negative floats: uint bit-pattern compare == float compare
    atomicMax(&pa_bits[b * NMAX + js], __float_as_uint(align));
    atomicMax(&po_bits[b * NMAX + js], __float_as_uint(iou));
}

// One block per 256 anchors: writes EVERY output element (no out memset needed).
// Score rows zeroed cooperatively with coalesced float4 stores, then one-hot scatter.
__global__ __launch_bounds__(256) void finalize_kernel(
    const int*   __restrict__ gt_labels,
    const float* __restrict__ gt_bboxes,
    const int* __restrict__ assigned_j,
    const float* __restrict__ a_align,
    const unsigned int* __restrict__ pa_bits, const unsigned int* __restrict__ po_bits,
    float* __restrict__ out)
{
    int t = threadIdx.x;
    int idx = blockIdx.x * 256 + t;          // BS*NA divisible by 256 -> no bounds check
    int b = idx / NA;
    int js = assigned_j[idx];
    bool pos = js >= 0;
    int j0 = pos ? js : 0;   // argmax of all-zero mask_pos -> gt 0
    int lab = gt_labels[b * NMAX + j0];

    out[OFF_LBL + idx] = pos ? (float)lab : (float)NC;

    float4 gb = ((const float4*)gt_bboxes)[b * NMAX + j0];
    ((float4*)(out + OFF_BOX))[idx] = gb;

    out[OFF_POS + idx] = pos ? 1.f : 0.f;

    // cooperative zero of this block's 256*80-float score region (fully coalesced)
    float4* sc = (float4*)(out + OFF_SCR + (size_t)blockIdx.x * 256 * NC);
    float4 z = make_float4(0.f, 0.f, 0.f, 0.f);
    #pragma unroll
    for (int i = 0; i < 256 * NC / 4 / 256; i++)
        sc[t + i * 256] = z;
    __syncthreads();  // order zero-fill before one-hot scatter (cross-thread same line)

    if (pos) {
        float pa = __uint_as_float(pa_bits[b * NMAX + js]);
        float po = __uint_as_float(po_bits[b * NMAX + js]);
        float norm = a_align[idx] * po / (pa + EPSF);
        out[OFF_SCR + (size_t)idx * NC + lab] = norm;
    }
}

extern "C" void kernel_launch(void* const* d_in, const int* in_sizes, int n_in,
                              void* d_out, int out_size, void* d_ws, size_t ws_size,
                              hipStream_t stream) {
    const float* pred_scores   = (const float*)d_in[0];
    const float* pred_bboxes   = (const float*)d_in[1];
    const float* anchor_points = (const float*)d_in[2];
    const int*   gt_labels     = (const int*)d_in[3];
    const float* gt_bboxes     = (const float*)d_in[4];
    const float* mask_gt       = (const float*)d_in[5];

    char* ws = (char*)d_ws;
    const size_t NBA = (size_t)BS * NA;           // 268800
    // layout: [claims NBA u32][pa 3200][po 3200][assigned_j NBA][a_align NBA]
    //         [strip_off 65 (pad 512B)][sAP NA f2][sIdx NA i32]
    unsigned int* claims   = (unsigned int*)(ws);
    unsigned int* pa_bits  = (unsigned int*)(ws + NBA * 4);
    unsigned int* po_bits  = (unsigned int*)(ws + NBA * 4 + (size_t)BS * NMAX * 4);
    int*   assigned_j = (int*)(ws + NBA * 4 + (size_t)BS * NMAX * 8);
    float* a_align    = (float*)(ws + NBA * 8 + (size_t)BS * NMAX * 8);
    size_t off5 = NBA * 12 + (size_t)BS * NMAX * 8;
    int*    strip_off = (int*)(ws + off5);
    float2* sAP       = (float2*)(ws + off5 + 512);
    int*    sIdx      = (int*)(ws + off5 + 512 + (size_t)NA * 8);

    float* out = (float*)d_out;

    // ws is poisoned 0xAA before every timed launch -> one contiguous re-zero
    // (claims + pa + po). d_out needs no memset: finalize writes every element.
    hipMemsetAsync(claims, 0, NBA * 4 + (size_t)BS * NMAX * 8, stream);

    bin_kernel<<<1, 256, 0, stream>>>(anchor_points, strip_off, sAP, sIdx);

    topk_kernel<<<BS * NMAX, 256, 0, stream>>>(
        pred_scores, pred_bboxes, gt_labels, gt_bboxes, mask_gt,
        strip_off, sAP, sIdx, claims);

    dim3 rgrid((NA + 255) / 256, BS);
    resolve_kernel<<<rgrid, 256, 0, stream>>>(
        pred_scores, pred_bboxes, gt_labels, gt_bboxes, claims,
        assigned_j, a_align, pa_bits, po_bits);

    finalize_kernel<<<(int)(NBA / 256), 256, 0, stream>>>(
        gt_labels, gt_bboxes, assigned_j, a_align, pa_bits, po_bits, out);
}

// Round 5
// 233.563 us; speedup vs baseline: 1.0439x; 1.0439x over previous
//
#include <hip/hip_runtime.h>

#define BS 32
#define NA 8400
#define NMAX 100
#define NC 80
#define TOPK 13
#define EPSF 1e-9f
#define WCAP 1024    // per-wave candidate cap; true max ~400 (mean ~60)
#define NSTRIP 64
#define STRIP_INV 0.1f   // 10px y-strips over [0,640)

// out layout (float32, concatenated in reference return order)
#define OFF_LBL  0
#define OFF_BOX  (BS*NA)                       // 268800
#define OFF_SCR  (BS*NA + BS*NA*4)             // 1344000
#define OFF_POS  (BS*NA + BS*NA*4 + BS*NA*NC)  // 22848000

__device__ __forceinline__ float iou_fn(float gx1, float gy1, float gx2, float gy2,
                                        float px1, float py1, float px2, float py2) {
    float lx = fmaxf(gx1, px1), ly = fmaxf(gy1, py1);
    float rx = fminf(gx2, px2), ry = fminf(gy2, py2);
    float w = fmaxf(rx - lx, 0.f), h = fmaxf(ry - ly, 0.f);
    float inter = w * h;
    float aa = (gx2 - gx1) * (gy2 - gy1);
    float ab = (px2 - px1) * (py2 - py1);
    return inter / (aa + ab - inter + EPSF);
}

// Single block, 1024 threads: bin anchors into 64 y-strips (strip-sorted
// (x,y)+index arrays). Wave-shuffle prefix over the 64 strip counts.
__global__ __launch_bounds__(1024) void bin_kernel(
    const float* __restrict__ anchor_points,
    int* __restrict__ strip_off, float2* __restrict__ sAP, int* __restrict__ sIdx)
{
    __shared__ int cnt[NSTRIP];
    __shared__ int cur[NSTRIP];
    int t = threadIdx.x;
    if (t < NSTRIP) cnt[t] = 0;
    __syncthreads();
    const float2* ap2 = (const float2*)anchor_points;
    for (int a = t; a < NA; a += 1024) {
        int s = (int)(ap2[a].y * STRIP_INV);
        s = s < 0 ? 0 : (s > NSTRIP - 1 ? NSTRIP - 1 : s);
        atomicAdd(&cnt[s], 1);
    }
    __syncthreads();
    if (t < 64) {
        int v = cnt[t];
        int inc = v;
        #pragma unroll
        for (int d = 1; d < 64; d <<= 1) {
            int o = __shfl_up(inc, d, 64);
            if (t >= d) inc += o;
        }
        int excl = inc - v;
        cur[t] = excl; strip_off[t] = excl;
        if (t == 63) strip_off[64] = inc;   // == NA
    }
    __syncthreads();
    for (int a = t; a < NA; a += 1024) {
        float2 p = ap2[a];
        int s = (int)(p.y * STRIP_INV);
        s = s < 0 ? 0 : (s > NSTRIP - 1 ? NSTRIP - 1 : s);
        int pos = atomicAdd(&cur[s], 1);
        sAP[pos] = p;
        sIdx[pos] = a;
    }
}

// ONE WAVE PER (b,j) GT ROW, 4 rows per block. Zero __syncthreads, zero
// LDS atomics (per-wave private LDS slice; single-wave access is coherent).
// Phase A: scan only y-strips overlapping (gy1,gy2); ballot-compact hit
//          indices into the wave's LDS list.
// Phase B: ~60 candidates -> 1 dense iteration; scattered pred loads with
//          full MLP; per-lane sorted top-13 register list.
// Phase C: 13 rounds of 64-lane butterfly max + winner shift-down (static
//          register indexing). One packed global atomic per pick.
// Key packing: (metric_bits<<32)|(NA-idx) -> u64 order == value desc, index
// asc (exact jax top_k tie-break). 4 serial chains/block overlap across waves.
__global__ __launch_bounds__(256) void topk_kernel(
    const float* __restrict__ pred_scores,   // BS,NA,NC
    const float* __restrict__ pred_bboxes,   // BS,NA,4
    const int*   __restrict__ gt_labels,     // BS,NMAX,1
    const float* __restrict__ gt_bboxes,     // BS,NMAX,4
    const float* __restrict__ mask_gt,       // BS,NMAX,1
    const int*   __restrict__ strip_off,
    const float2* __restrict__ sAP,
    const int*   __restrict__ sIdx,
    unsigned int* __restrict__ claims)       // BS,NA packed: (count<<16)|jsum
{
    __shared__ unsigned short aidx[4][WCAP];
    int wave = threadIdx.x >> 6;
    int lane = threadIdx.x & 63;
    int row = blockIdx.x * 4 + wave;         // 800 blocks * 4 waves == BS*NMAX
    int b = row / NMAX, j = row % NMAX;
    if (mask_gt[row] <= 0.f) return;         // wave-uniform exit, no barriers used

    const float* gbp = gt_bboxes + (size_t)row * 4;
    float gx1 = gbp[0], gy1 = gbp[1], gx2 = gbp[2], gy2 = gbp[3];
    int lab = gt_labels[row];

    // strip range covering (gy1,gy2): float mul + trunc are monotone, so any
    // anchor passing the exact test lies within [s_lo, s_hi].
    int s_lo = (int)(gy1 * STRIP_INV); s_lo = s_lo < 0 ? 0 : (s_lo > NSTRIP-1 ? NSTRIP-1 : s_lo);
    int s_hi = (int)(gy2 * STRIP_INV); s_hi = s_hi < 0 ? 0 : (s_hi > NSTRIP-1 ? NSTRIP-1 : s_hi);
    int lo = strip_off[s_lo], hi = strip_off[s_hi + 1];

    // Phase A: ballot-compact in-gt anchor indices (wave-private, no atomics)
    int cnt = 0;
    for (int base = lo; base < hi; base += 64) {
        int p = base + lane;
        bool hit = false; int a = 0;
        if (p < hi) {
            float2 ap = sAP[p];
            a = sIdx[p];
            hit = (ap.x - gx1 > EPSF) && (ap.y - gy1 > EPSF) &&
                  (gx2 - ap.x > EPSF) && (gy2 - ap.y > EPSF);
        }
        unsigned long long mb = __ballot(hit);
        if (hit) {
            int my = cnt + __popcll(mb & ((1ULL << lane) - 1ULL));
            if (my < WCAP) aidx[wave][my] = (unsigned short)a;
        }
        cnt += __popcll(mb);   // wave-uniform
    }
    if (cnt > WCAP) cnt = WCAP;

    // Phase B: dense metric pass, per-lane sorted top-13 in registers
    unsigned long long loc[TOPK];
    #pragma unroll
    for (int i = 0; i < TOPK; i++) loc[i] = 0ULL;
    const float4* pb4 = (const float4*)pred_bboxes;
    for (int p = lane; p < cnt; p += 64) {
        int a = aidx[wave][p];
        float4 pb = pb4[b * NA + a];
        float s = pred_scores[((size_t)b * NA + a) * NC + lab];
        float iou = iou_fn(gx1, gy1, gx2, gy2, pb.x, pb.y, pb.z, pb.w);
        float i2 = iou * iou;
        float m = s * (i2 * i2 * i2);
        if (m > 0.f) {
            unsigned long long key =
                ((unsigned long long)__float_as_uint(m) << 32) |
                (unsigned int)(NA - a);
            #pragma unroll
            for (int i = 0; i < TOPK; i++) {
                if (key > loc[i]) { unsigned long long tmp = loc[i]; loc[i] = key; key = tmp; }
            }
        }
    }

    // Phase C: 13 extract-max rounds; winner lane shifts its list down
    for (int r = 0; r < TOPK; r++) {
        unsigned long long h = loc[0];
        unsigned long long m = h;
        #pragma unroll
        for (int s = 32; s > 0; s >>= 1) {
            unsigned long long o = __shfl_xor(m, s, 64);
            m = o > m ? o : m;
        }
        if (m == 0ULL) break;  // fewer than 13 positive candidates (wave-uniform)
        unsigned long long ball = __ballot(h == m);  // keys distinct -> one lane
        if (lane == (int)__builtin_ctzll(ball)) {
            #pragma unroll
            for (int i = 0; i < TOPK - 1; i++) loc[i] = loc[i + 1];
            loc[TOPK - 1] = 0ULL;
            int a = NA - (int)(unsigned int)(m & 0xFFFFFFFFULL);
            atomicAdd(&claims[b * NA + a], (1u << 16) | (unsigned int)j);
        }
    }
}

// Grid (ceil(NA/256), BS). Stage this batch's gt boxes+labels in LDS so the
// multi-claim argmax loop (and final gt lookup) never touches global memory.
__global__ __launch_bounds__(256) void resolve_kernel(
    const float* __restrict__ pred_scores,
    const float* __restrict__ pred_bboxes,
    const int*   __restrict__ gt_labels,
    const float* __restrict__ gt_bboxes,
    const unsigned int* __restrict__ claims,
    int* __restrict__ assigned_j, float* __restrict__ a_align,
    unsigned int* __restrict__ pa_bits, unsigned int* __restrict__ po_bits)
{
    __shared__ float4 gtb[NMAX];
    __shared__ int    glab[NMAX];
    int b = blockIdx.y;
    int t = threadIdx.x;
    if (t < NMAX) {
        gtb[t]  = ((const float4*)gt_bboxes)[b * NMAX + t];
        glab[t] = gt_labels[b * NMAX + t];
    }
    __syncthreads();

    int ai = blockIdx.x * 256 + t;
    if (ai >= NA) return;
    int idx = b * NA + ai;
    unsigned int pk = claims[idx];
    if (pk == 0u) { assigned_j[idx] = -1; a_align[idx] = 0.f; return; }

    float4 pb = ((const float4*)pred_bboxes)[idx];

    int js;
    if ((pk >> 16) == 1u) {
        js = (int)(pk & 0xFFFFu);
    } else {
        // reference: overlaps.argmax(axis=1) over ALL gts, first-max wins
        float best = -1.f; js = 0;
        for (int j = 0; j < NMAX; j++) {
            float4 g = gtb[j];
            float v = iou_fn(g.x, g.y, g.z, g.w, pb.x, pb.y, pb.z, pb.w);
            if (v > best) { best = v; js = j; }
        }
    }
    float4 g = gtb[js];
    float iou = iou_fn(g.x, g.y, g.z, g.w, pb.x, pb.y, pb.z, pb.w);
    int lab = glab[js];
    float s = pred_scores[(size_t)idx * NC + lab];
    float i2 = iou * iou;
    float align = s * (i2 * i2 * i2);   // UNMASKED align metric (reference semantics)
    assigned_j[idx] = js; a_align[idx] = align;
    // non-negative floats: uint bit-pattern compare == float compare
    atomicMax(&pa_bits[b * NMAX + js], __float_as_uint(align));
    atomicMax(&po_bits[b * NMAX + js], __float_as_uint(iou));
}

// One block per 256 anchors: writes EVERY output element (no out memset needed).
// Score rows zeroed cooperatively with coalesced float4 stores, then one-hot scatter.
__global__ __launch_bounds__(256) void finalize_kernel(
    const int*   __restrict__ gt_labels,
    const float* __restrict__ gt_bboxes,
    const int* __restrict__ assigned_j,
    const float* __restrict__ a_align,
    const unsigned int* __restrict__ pa_bits, const unsigned int* __restrict__ po_bits,
    float* __restrict__ out)
{
    int t = threadIdx.x;
    int idx = blockIdx.x * 256 + t;          // BS*NA divisible by 256 -> no bounds check
    int b = idx / NA;
    int js = assigned_j[idx];
    bool pos = js >= 0;
    int j0 = pos ? js : 0;   // argmax of all-zero mask_pos -> gt 0
    int lab = gt_labels[b * NMAX + j0];

    out[OFF_LBL + idx] = pos ? (float)lab : (float)NC;

    float4 gb = ((const float4*)gt_bboxes)[b * NMAX + j0];
    ((float4*)(out + OFF_BOX))[idx] = gb;

    out[OFF_POS + idx] = pos ? 1.f : 0.f;

    // cooperative zero of this block's 256*80-float score region (fully coalesced)
    float4* sc = (float4*)(out + OFF_SCR + (size_t)blockIdx.x * 256 * NC);
    float4 z = make_float4(0.f, 0.f, 0.f, 0.f);
    #pragma unroll
    for (int i = 0; i < 256 * NC / 4 / 256; i++)
        sc[t + i * 256] = z;
    __syncthreads();  // order zero-fill before one-hot scatter (cross-thread same line)

    if (pos) {
        float pa = __uint_as_float(pa_bits[b * NMAX + js]);
        float po = __uint_as_float(po_bits[b * NMAX + js]);
        float norm = a_align[idx] * po / (pa + EPSF);
        out[OFF_SCR + (size_t)idx * NC + lab] = norm;
    }
}

extern "C" void kernel_launch(void* const* d_in, const int* in_sizes, int n_in,
                              void* d_out, int out_size, void* d_ws, size_t ws_size,
                              hipStream_t stream) {
    const float* pred_scores   = (const float*)d_in[0];
    const float* pred_bboxes   = (const float*)d_in[1];
    const float* anchor_points = (const float*)d_in[2];
    const int*   gt_labels     = (const int*)d_in[3];
    const float* gt_bboxes     = (const float*)d_in[4];
    const float* mask_gt       = (const float*)d_in[5];

    char* ws = (char*)d_ws;
    const size_t NBA = (size_t)BS * NA;           // 268800
    // layout: [claims NBA u32][pa 3200][po 3200][assigned_j NBA][a_align NBA]
    //         [strip_off 65 (pad 512B)][sAP NA f2][sIdx NA i32]
    unsigned int* claims   = (unsigned int*)(ws);
    unsigned int* pa_bits  = (unsigned int*)(ws + NBA * 4);
    unsigned int* po_bits  = (unsigned int*)(ws + NBA * 4 + (size_t)BS * NMAX * 4);
    int*   assigned_j = (int*)(ws + NBA * 4 + (size_t)BS * NMAX * 8);
    float* a_align    = (float*)(ws + NBA * 8 + (size_t)BS * NMAX * 8);
    size_t off5 = NBA * 12 + (size_t)BS * NMAX * 8;
    int*    strip_off = (int*)(ws + off5);
    float2* sAP       = (float2*)(ws + off5 + 512);
    int*    sIdx      = (int*)(ws + off5 + 512 + (size_t)NA * 8);

    float* out = (float*)d_out;

    // ws is poisoned 0xAA before every timed launch -> one contiguous re-zero
    // (claims + pa + po). d_out needs no memset: finalize writes every element.
    hipMemsetAsync(claims, 0, NBA * 4 + (size_t)BS * NMAX * 8, stream);

    bin_kernel<<<1, 1024, 0, stream>>>(anchor_points, strip_off, sAP, sIdx);

    topk_kernel<<<BS * NMAX / 4, 256, 0, stream>>>(
        pred_scores, pred_bboxes, gt_labels, gt_bboxes, mask_gt,
        strip_off, sAP, sIdx, claims);

    dim3 rgrid((NA + 255) / 256, BS);
    resolve_kernel<<<rgrid, 256, 0, stream>>>(
        pred_scores, pred_bboxes, gt_labels, gt_bboxes, claims,
        assigned_j, a_align, pa_bits, po_bits);

    finalize_kernel<<<(int)(NBA / 256), 256, 0, stream>>>(
        gt_labels, gt_bboxes, assigned_j, a_align, pa_bits, po_bits, out);
}

// Round 6
// 230.218 us; speedup vs baseline: 1.0591x; 1.0145x over previous
//
#include <hip/hip_runtime.h>

#define BS 32
#define NA 8400
#define NMAX 100
#define NC 80
#define TOPK 13
#define EPSF 1e-9f
#define WCAP 1024    // per-wave candidate cap; true max ~400 (mean ~60)
#define NSTRIP 64
#define STRIP_INV 0.1f   // 10px y-strips over [0,640)

// out layout (float32, concatenated in reference return order)
#define OFF_LBL  0
#define OFF_BOX  (BS*NA)                       // 268800
#define OFF_SCR  (BS*NA + BS*NA*4)             // 1344000
#define OFF_POS  (BS*NA + BS*NA*4 + BS*NA*NC)  // 22848000

#define NBA_ELEMS (BS*NA)                      // 268800
#define ZERO_U32  (NBA_ELEMS + 2*BS*NMAX)      // claims + pa + po, contiguous u32s

__device__ __forceinline__ float iou_fn(float gx1, float gy1, float gx2, float gy2,
                                        float px1, float py1, float px2, float py2) {
    float lx = fmaxf(gx1, px1), ly = fmaxf(gy1, py1);
    float rx = fminf(gx2, px2), ry = fminf(gy2, py2);
    float w = fmaxf(rx - lx, 0.f), h = fmaxf(ry - ly, 0.f);
    float inter = w * h;
    float aa = (gx2 - gx1) * (gy2 - gy1);
    float ab = (px2 - px1) * (py2 - py1);
    return inter / (aa + ab - inter + EPSF);
}

// Grid 9 x 1024. Block 0: bin anchors into 64 y-strips, emitting strip-sorted
// float4 (x, y, idx-bits, 0) so topk's phase A is ONE 16B coalesced load per
// anchor. Blocks 1..8: grid-stride zero of claims+pa+po (replaces the memset
// dispatch; no interdependence with block 0 inside this kernel).
__global__ __launch_bounds__(1024) void bin_zero_kernel(
    const float* __restrict__ anchor_points,
    int* __restrict__ strip_off, float4* __restrict__ sAPI,
    unsigned int* __restrict__ zero_base)
{
    int t = threadIdx.x;
    if (blockIdx.x != 0) {
        // blocks 1..8: zero 275200 u32 = 68800 uint4 with 8192 threads
        uint4* z = (uint4*)zero_base;
        const int nz = ZERO_U32 / 4;
        uint4 zz = make_uint4(0u, 0u, 0u, 0u);
        for (int i = (blockIdx.x - 1) * 1024 + t; i < nz; i += 8 * 1024)
            z[i] = zz;
        return;
    }

    __shared__ int cnt[NSTRIP];
    __shared__ int cur[NSTRIP];
    if (t < NSTRIP) cnt[t] = 0;
    __syncthreads();
    const float2* ap2 = (const float2*)anchor_points;
    for (int a = t; a < NA; a += 1024) {
        int s = (int)(ap2[a].y * STRIP_INV);
        s = s < 0 ? 0 : (s > NSTRIP - 1 ? NSTRIP - 1 : s);
        atomicAdd(&cnt[s], 1);
    }
    __syncthreads();
    if (t < 64) {
        int v = cnt[t];
        int inc = v;
        #pragma unroll
        for (int d = 1; d < 64; d <<= 1) {
            int o = __shfl_up(inc, d, 64);
            if (t >= d) inc += o;
        }
        int excl = inc - v;
        cur[t] = excl; strip_off[t] = excl;
        if (t == 63) strip_off[64] = inc;   // == NA
    }
    __syncthreads();
    for (int a = t; a < NA; a += 1024) {
        float2 p = ap2[a];
        int s = (int)(p.y * STRIP_INV);
        s = s < 0 ? 0 : (s > NSTRIP - 1 ? NSTRIP - 1 : s);
        int pos = atomicAdd(&cur[s], 1);
        sAPI[pos] = make_float4(p.x, p.y, __int_as_float(a), 0.f);
    }
}

// ONE WAVE PER (b,j) GT ROW, 4 rows per block. Zero __syncthreads, zero
// LDS atomics (per-wave private LDS slice; single-wave access is coherent).
// Phase A: scan only y-strips overlapping (gy1,gy2); one float4 load per
//          anchor; ballot-compact hit indices into the wave's LDS list.
// Phase B: ~60 candidates -> 1 dense iteration; scattered pred loads with
//          full MLP; per-lane sorted top-13 register list.
// Phase C: 13 rounds of 64-lane butterfly max + winner shift-down (static
//          register indexing). One packed global atomic per pick.
// Key packing: (metric_bits<<32)|(NA-idx) -> u64 order == value desc, index
// asc (exact jax top_k tie-break). 4 serial chains/block overlap across waves.
__global__ __launch_bounds__(256) void topk_kernel(
    const float* __restrict__ pred_scores,   // BS,NA,NC
    const float* __restrict__ pred_bboxes,   // BS,NA,4
    const int*   __restrict__ gt_labels,     // BS,NMAX,1
    const float* __restrict__ gt_bboxes,     // BS,NMAX,4
    const float* __restrict__ mask_gt,       // BS,NMAX,1
    const int*   __restrict__ strip_off,
    const float4* __restrict__ sAPI,
    unsigned int* __restrict__ claims)       // BS,NA packed: (count<<16)|jsum
{
    __shared__ unsigned short aidx[4][WCAP];
    int wave = threadIdx.x >> 6;
    int lane = threadIdx.x & 63;
    int row = blockIdx.x * 4 + wave;         // 800 blocks * 4 waves == BS*NMAX
    int b = row / NMAX, j = row % NMAX;
    if (mask_gt[row] <= 0.f) return;         // wave-uniform exit, no barriers used

    const float* gbp = gt_bboxes + (size_t)row * 4;
    float gx1 = gbp[0], gy1 = gbp[1], gx2 = gbp[2], gy2 = gbp[3];
    int lab = gt_labels[row];

    // strip range covering (gy1,gy2): float mul + trunc are monotone, so any
    // anchor passing the exact test lies within [s_lo, s_hi].
    int s_lo = (int)(gy1 * STRIP_INV); s_lo = s_lo < 0 ? 0 : (s_lo > NSTRIP-1 ? NSTRIP-1 : s_lo);
    int s_hi = (int)(gy2 * STRIP_INV); s_hi = s_hi < 0 ? 0 : (s_hi > NSTRIP-1 ? NSTRIP-1 : s_hi);
    int lo = strip_off[s_lo], hi = strip_off[s_hi + 1];

    // Phase A: ballot-compact in-gt anchor indices (wave-private, no atomics)
    int cnt = 0;
    for (int base = lo; base < hi; base += 64) {
        int p = base + lane;
        bool hit = false; int a = 0;
        if (p < hi) {
            float4 ap = sAPI[p];
            a = __float_as_int(ap.z);
            hit = (ap.x - gx1 > EPSF) && (ap.y - gy1 > EPSF) &&
                  (gx2 - ap.x > EPSF) && (gy2 - ap.y > EPSF);
        }
        unsigned long long mb = __ballot(hit);
        if (hit) {
            int my = cnt + __popcll(mb & ((1ULL << lane) - 1ULL));
            if (my < WCAP) aidx[wave][my] = (unsigned short)a;
        }
        cnt += __popcll(mb);   // wave-uniform
    }
    if (cnt > WCAP) cnt = WCAP;

    // Phase B: dense metric pass, per-lane sorted top-13 in registers
    unsigned long long loc[TOPK];
    #pragma unroll
    for (int i = 0; i < TOPK; i++) loc[i] = 0ULL;
    const float4* pb4 = (const float4*)pred_bboxes;
    for (int p = lane; p < cnt; p += 64) {
        int a = aidx[wave][p];
        float4 pb = pb4[b * NA + a];
        float s = pred_scores[((size_t)b * NA + a) * NC + lab];
        float iou = iou_fn(gx1, gy1, gx2, gy2, pb.x, pb.y, pb.z, pb.w);
        float i2 = iou * iou;
        float m = s * (i2 * i2 * i2);
        if (m > 0.f) {
            unsigned long long key =
                ((unsigned long long)__float_as_uint(m) << 32) |
                (unsigned int)(NA - a);
            #pragma unroll
            for (int i = 0; i < TOPK; i++) {
                if (key > loc[i]) { unsigned long long tmp = loc[i]; loc[i] = key; key = tmp; }
            }
        }
    }

    // Phase C: 13 extract-max rounds; winner lane shifts its list down
    for (int r = 0; r < TOPK; r++) {
        unsigned long long h = loc[0];
        unsigned long long m = h;
        #pragma unroll
        for (int s = 32; s > 0; s >>= 1) {
            unsigned long long o = __shfl_xor(m, s, 64);
            m = o > m ? o : m;
        }
        if (m == 0ULL) break;  // fewer than 13 positive candidates (wave-uniform)
        unsigned long long ball = __ballot(h == m);  // keys distinct -> one lane
        if (lane == (int)__builtin_ctzll(ball)) {
            #pragma unroll
            for (int i = 0; i < TOPK - 1; i++) loc[i] = loc[i + 1];
            loc[TOPK - 1] = 0ULL;
            int a = NA - (int)(unsigned int)(m & 0xFFFFFFFFULL);
            atomicAdd(&claims[b * NA + a], (1u << 16) | (unsigned int)j);
        }
    }
}

// Grid (ceil(NA/256), BS). Stage this batch's gt boxes+labels in LDS so the
// multi-claim argmax loop (and final gt lookup) never touches global memory.
__global__ __launch_bounds__(256) void resolve_kernel(
    const float* __restrict__ pred_scores,
    const float* __restrict__ pred_bboxes,
    const int*   __restrict__ gt_labels,
    const float* __restrict__ gt_bboxes,
    const unsigned int* __restrict__ claims,
    int* __restrict__ assigned_j, float* __restrict__ a_align,
    unsigned int* __restrict__ pa_bits, unsigned int* __restrict__ po_bits)
{
    __shared__ float4 gtb[NMAX];
    __shared__ int    glab[NMAX];
    int b = blockIdx.y;
    int t = threadIdx.x;
    if (t < NMAX) {
        gtb[t]  = ((const float4*)gt_bboxes)[b * NMAX + t];
        glab[t] = gt_labels[b * NMAX + t];
    }
    __syncthreads();

    int ai = blockIdx.x * 256 + t;
    if (ai >= NA) return;
    int idx = b * NA + ai;
    unsigned int pk = claims[idx];
    if (pk == 0u) { assigned_j[idx] = -1; a_align[idx] = 0.f; return; }

    float4 pb = ((const float4*)pred_bboxes)[idx];

    int js; float iou;
    if ((pk >> 16) == 1u) {
        js = (int)(pk & 0xFFFFu);
        float4 g = gtb[js];
        iou = iou_fn(g.x, g.y, g.z, g.w, pb.x, pb.y, pb.z, pb.w);
    } else {
        // reference: overlaps.argmax(axis=1) over ALL gts, first-max wins.
        // best == iou at js (same fn, same inputs, deterministic) -> reuse.
        float best = -1.f; js = 0;
        for (int j = 0; j < NMAX; j++) {
            float4 g = gtb[j];
            float v = iou_fn(g.x, g.y, g.z, g.w, pb.x, pb.y, pb.z, pb.w);
            if (v > best) { best = v; js = j; }
        }
        iou = best;
    }
    int lab = glab[js];
    float s = pred_scores[(size_t)idx * NC + lab];
    float i2 = iou * iou;
    float align = s * (i2 * i2 * i2);   // UNMASKED align metric (reference semantics)
    assigned_j[idx] = js; a_align[idx] = align;
    // non-negative floats: uint bit-pattern compare == float compare
    atomicMax(&pa_bits[b * NMAX + js], __float_as_uint(align));
    atomicMax(&po_bits[b * NMAX + js], __float_as_uint(iou));
}

// One block per 256 anchors: writes EVERY output element (no out memset needed).
// Score rows zeroed cooperatively with coalesced float4 stores, then one-hot scatter.
__global__ __launch_bounds__(256) void finalize_kernel(
    const int*   __restrict__ gt_labels,
    const float* __restrict__ gt_bboxes,
    const int* __restrict__ assigned_j,
    const float* __restrict__ a_align,
    const unsigned int* __restrict__ pa_bits, const unsigned int* __restrict__ po_bits,
    float* __restrict__ out)
{
    int t = threadIdx.x;
    int idx = blockIdx.x * 256 + t;          // BS*NA divisible by 256 -> no bounds check
    int b = idx / NA;
    int js = assigned_j[idx];
    bool pos = js >= 0;
    int j0 = pos ? js : 0;   // argmax of all-zero mask_pos -> gt 0
    int lab = gt_labels[b * NMAX + j0];

    out[OFF_LBL + idx] = pos ? (float)lab : (float)NC;

    float4 gb = ((const float4*)gt_bboxes)[b * NMAX + j0];
    ((float4*)(out + OFF_BOX))[idx] = gb;

    out[OFF_POS + idx] = pos ? 1.f : 0.f;

    // cooperative zero of this block's 256*80-float score region (fully coalesced)
    float4* sc = (float4*)(out + OFF_SCR + (size_t)blockIdx.x * 256 * NC);
    float4 z = make_float4(0.f, 0.f, 0.f, 0.f);
    #pragma unroll
    for (int i = 0; i < 256 * NC / 4 / 256; i++)
        sc[t + i * 256] = z;
    __syncthreads();  // order zero-fill before one-hot scatter (cross-thread same line)

    if (pos) {
        float pa = __uint_as_float(pa_bits[b * NMAX + js]);
        float po = __uint_as_float(po_bits[b * NMAX + js]);
        float norm = a_align[idx] * po / (pa + EPSF);
        out[OFF_SCR + (size_t)idx * NC + lab] = norm;
    }
}

extern "C" void kernel_launch(void* const* d_in, const int* in_sizes, int n_in,
                              void* d_out, int out_size, void* d_ws, size_t ws_size,
                              hipStream_t stream) {
    const float* pred_scores   = (const float*)d_in[0];
    const float* pred_bboxes   = (const float*)d_in[1];
    const float* anchor_points = (const float*)d_in[2];
    const int*   gt_labels     = (const int*)d_in[3];
    const float* gt_bboxes     = (const float*)d_in[4];
    const float* mask_gt       = (const float*)d_in[5];

    char* ws = (char*)d_ws;
    const size_t NBA = (size_t)BS * NA;           // 268800
    // layout: [claims NBA u32][pa 3200][po 3200][assigned_j NBA][a_align NBA]
    //         [strip_off 65 ints (pad 512B)][sAPI NA float4]
    unsigned int* claims   = (unsigned int*)(ws);
    unsigned int* pa_bits  = (unsigned int*)(ws + NBA * 4);
    unsigned int* po_bits  = (unsigned int*)(ws + NBA * 4 + (size_t)BS * NMAX * 4);
    int*   assigned_j = (int*)(ws + NBA * 4 + (size_t)BS * NMAX * 8);
    float* a_align    = (float*)(ws + NBA * 8 + (size_t)BS * NMAX * 8);
    size_t off5 = NBA * 12 + (size_t)BS * NMAX * 8;
    int*    strip_off = (int*)(ws + off5);
    float4* sAPI      = (float4*)(ws + off5 + 512);

    float* out = (float*)d_out;

    // ws is poisoned 0xAA before every timed launch; bin_zero_kernel re-zeros
    // claims+pa+po in parallel with binning (blocks 1..8 vs block 0).
    // d_out needs no memset: finalize writes every output element.
    bin_zero_kernel<<<9, 1024, 0, stream>>>(anchor_points, strip_off, sAPI, claims);

    topk_kernel<<<BS * NMAX / 4, 256, 0, stream>>>(
        pred_scores, pred_bboxes, gt_labels, gt_bboxes, mask_gt,
        strip_off, sAPI, claims);

    dim3 rgrid((NA + 255) / 256, BS);
    resolve_kernel<<<rgrid, 256, 0, stream>>>(
        pred_scores, pred_bboxes, gt_labels, gt_bboxes, claims,
        assigned_j, a_align, pa_bits, po_bits);

    finalize_kernel<<<(int)(NBA / 256), 256, 0, stream>>>(
        gt_labels, gt_bboxes, assigned_j, a_align, pa_bits, po_bits, out);
}